// Round 1
// baseline (340.253 us; speedup 1.0000x reference)
//
#include <hip/hip_runtime.h>

#define LIF_THRESH 0.5f
#define LIF_DECAY  0.25f

__device__ __forceinline__ void lif_step(float& mem, float& spike, float xv) {
    mem = mem * LIF_DECAY * (1.0f - spike) + xv;
    spike = (mem > LIF_THRESH) ? 1.0f : 0.0f;
}

// x laid out [T=4][N] float; out same. Each thread handles one float4 (4
// contiguous elements) per grid-stride iteration, carrying the T=4
// recurrence entirely in registers.
__global__ __launch_bounds__(256) void lif_kernel(const float4* __restrict__ x,
                                                  float4* __restrict__ out,
                                                  long long n4, long long s4) {
    long long i   = (long long)blockIdx.x * blockDim.x + threadIdx.x;
    long long gsz = (long long)gridDim.x * blockDim.x;
    for (; i < n4; i += gsz) {
        float4 mem   = make_float4(0.f, 0.f, 0.f, 0.f);
        float4 spike = make_float4(0.f, 0.f, 0.f, 0.f);
#pragma unroll
        for (int t = 0; t < 4; ++t) {
            float4 xv = x[(long long)t * s4 + i];
            lif_step(mem.x, spike.x, xv.x);
            lif_step(mem.y, spike.y, xv.y);
            lif_step(mem.z, spike.z, xv.z);
            lif_step(mem.w, spike.w, xv.w);
            out[(long long)t * s4 + i] = spike;
        }
    }
}

extern "C" void kernel_launch(void* const* d_in, const int* in_sizes, int n_in,
                              void* d_out, int out_size, void* d_ws, size_t ws_size,
                              hipStream_t stream) {
    const float* x = (const float*)d_in[0];
    float* out = (float*)d_out;

    const long long total = in_sizes[0];      // T*B*C*H*W = 51,380,224
    const long long T = 4;
    const long long N = total / T;            // 12,845,056 (divisible by 4)
    const long long n4 = N / 4;               // float4 items per timestep
    const long long s4 = n4;                  // timestep stride in float4 units

    const int block = 256;
    long long blocks_needed = (n4 + block - 1) / block;
    int grid = (int)((blocks_needed < 2048) ? blocks_needed : 2048);

    lif_kernel<<<grid, block, 0, stream>>>((const float4*)x, (float4*)out, n4, s4);
}

// Round 2
// 319.933 us; speedup vs baseline: 1.0635x; 1.0635x over previous
//
#include <hip/hip_runtime.h>

typedef float f32x4 __attribute__((ext_vector_type(4)));

#define LIF_THRESH 0.5f
#define LIF_DECAY  0.25f

// x laid out [T=4][N] float, out same. One thread = one float4 column through
// all 4 timesteps. All loads issued before compute (64B MLP/thread),
// nontemporal hints since the 411MB stream exceeds L3.
__global__ __launch_bounds__(256) void lif_kernel(const f32x4* __restrict__ x,
                                                  f32x4* __restrict__ out,
                                                  int n4, int s4) {
    int i = blockIdx.x * 256 + threadIdx.x;
    if (i >= n4) return;

    const f32x4* xp = x + i;
    f32x4* op = out + i;

    f32x4 x0 = __builtin_nontemporal_load(xp);
    f32x4 x1 = __builtin_nontemporal_load(xp + s4);
    f32x4 x2 = __builtin_nontemporal_load(xp + 2 * s4);
    f32x4 x3 = __builtin_nontemporal_load(xp + 3 * s4);

    f32x4 s0, s1, s2, s3;
#pragma unroll
    for (int c = 0; c < 4; ++c) {
        float m, sp;
        m = x0[c];
        sp = (m > LIF_THRESH) ? 1.0f : 0.0f; s0[c] = sp;
        m = m * LIF_DECAY * (1.0f - sp) + x1[c];
        sp = (m > LIF_THRESH) ? 1.0f : 0.0f; s1[c] = sp;
        m = m * LIF_DECAY * (1.0f - sp) + x2[c];
        sp = (m > LIF_THRESH) ? 1.0f : 0.0f; s2[c] = sp;
        m = m * LIF_DECAY * (1.0f - sp) + x3[c];
        sp = (m > LIF_THRESH) ? 1.0f : 0.0f; s3[c] = sp;
    }

    __builtin_nontemporal_store(s0, op);
    __builtin_nontemporal_store(s1, op + s4);
    __builtin_nontemporal_store(s2, op + 2 * s4);
    __builtin_nontemporal_store(s3, op + 3 * s4);
}

extern "C" void kernel_launch(void* const* d_in, const int* in_sizes, int n_in,
                              void* d_out, int out_size, void* d_ws, size_t ws_size,
                              hipStream_t stream) {
    const float* x = (const float*)d_in[0];
    float* out = (float*)d_out;

    const int total = in_sizes[0];   // T*B*C*H*W = 51,380,224
    const int T = 4;
    const int N = total / T;         // 12,845,056
    const int n4 = N / 4;            // 3,211,264 float4 per timestep
    const int s4 = n4;

    const int block = 256;
    const int grid = (n4 + block - 1) / block;  // 12544 — exact, no tail

    lif_kernel<<<grid, block, 0, stream>>>((const f32x4*)x, (f32x4*)out, n4, s4);
}